// Round 7
// baseline (413.114 us; speedup 1.0000x reference)
//
#include <hip/hip_runtime.h>
#include <hip/hip_bf16.h>
#include <stdint.h>
#include <math.h>

// ---------------------------------------------------------------------------
// JointAttention: dual-stream rmsnorm -> QKV proj -> RoPE -> joint attention
// over concat(a, x) (4096 tokens, 16 q-heads, 4 kv-heads tiled h%4) -> out proj.
// All matmuls in bf16 MFMA, fp32 accumulate.
//
// R7:
//  - PV at FULL-RATE K=32 (R6 cycle model: 16x16x16 costs same cycles as
//    16x16x32 -> K=16 PV wasted half the matrix pipe). Trick: permute the
//    K-tile row order in the QK^T A-operand (g(jb,m) = 32*(jb>>1) + 8*(m>>2)
//    + 4*(jb&1) + (m&3)) so each lane's S^T C-frag values ARE its K=32
//    P^T B-frag (keys 32sb+8q+0..7) -- zero cross-lane movement, and V^T
//    A-frags become contiguous bf16x8 reads. 48 -> 28 MFMA/tile-wave.
//  - z=1 (key-slicing was occupancy-neutral in R5): normalize in-kernel,
//    combine kernel + OP/LS traffic gone.
//  - vtrans fused into gemm_qkv epilogue (direct packed 8B stores to VT).
//  - 4 launches total: prep, gemm_qkv, attn, gemm_out.
//  - LDS pad 72 -> 76 (permuted kf rows stay <=2-way conflicts).
// ---------------------------------------------------------------------------

#define NSEQ 2048
#define NJ   4096
#define DIMM 1024
#define LPAD 76

typedef __attribute__((ext_vector_type(4))) float f32x4;
typedef __attribute__((ext_vector_type(8))) short bf16x8;
typedef __attribute__((ext_vector_type(4))) short bf16x4;

__device__ __forceinline__ unsigned short f2bf(float f) {
  union { float f; uint32_t u; } v; v.f = f;
  return (unsigned short)((v.u + 0x7FFFu + ((v.u >> 16) & 1u)) >> 16);
}

__device__ __forceinline__ uint32_t pack2bf(float a, float b) {
  __hip_bfloat162 h = __float22bfloat162_rn(float2{a, b});
  union { __hip_bfloat162 h; uint32_t u; } c; c.h = h;
  return c.u;
}

#if defined(__has_builtin)
#if __has_builtin(__builtin_amdgcn_exp2f)
#define FAST_EXP2(x) __builtin_amdgcn_exp2f(x)
#endif
#endif
#ifndef FAST_EXP2
#define FAST_EXP2(x) exp2f(x)
#endif

// async global->LDS, 16B per lane; LDS dest = wave-uniform base + lane*16
__device__ __forceinline__ void glds16(const void* g, void* l) {
  __builtin_amdgcn_global_load_lds(
      (const __attribute__((address_space(1))) unsigned int*)g,
      (__attribute__((address_space(3))) unsigned int*)l, 16, 0, 0);
}

// ---------------- fused prep: rope tables + weight cast + rmsnorm ----------
// flat grid, block-uniform branch:
//   [0,256)        rope tables (fp64 trig)
//   [256,6400)     weight cast+transpose f32[1024][N] -> bf16[N][1024]
//   [6400,10496)   rmsnorm + bf16 cast
__global__ __launch_bounds__(256) void prep_kernel(
    const float* __restrict__ xa, const float* __restrict__ xx,
    const float* __restrict__ ga, const float* __restrict__ gx,
    const float* __restrict__ wqa, const float* __restrict__ wqx,
    const float* __restrict__ wkva, const float* __restrict__ wkvx,
    const float* __restrict__ woa, const float* __restrict__ wox,
    unsigned short* __restrict__ XN, unsigned short* __restrict__ WQT,
    unsigned short* __restrict__ WKVT, unsigned short* __restrict__ WOT,
    float* __restrict__ cosT, float* __restrict__ sinT) {
  __shared__ float tile[32][33];
  __shared__ float red[4];
  int bid = blockIdx.x, t = threadIdx.x;
  if (bid < 256) {
    int idx = bid * 256 + t;                    // exactly NSEQ*32
    int pos = idx >> 5, i = idx & 31;
    double inv = pow(10000.0, -(double)i / 32.0);
    double ang = (double)(2 * pos) * inv;       // t = pos * (4096/2048)
    cosT[idx] = (float)cos(ang);
    sinT[idx] = (float)sin(ang);
  } else if (bid < 6400) {
    int b = bid - 256;
    int z = b >> 10, yx = b & 1023;
    int n0 = (yx >> 5) * 32, k0 = (yx & 31) * 32;
    int s = z & 1, ty = z >> 1;
    int N = (ty == 1) ? 512 : 1024;
    if (n0 >= N) return;                        // block-uniform
    const float* src = (z == 0) ? wqa : (z == 1) ? wqx : (z == 2) ? wkva
                     : (z == 3) ? wkvx : (z == 4) ? woa : wox;
    unsigned short* dst = (ty == 0) ? WQT + (size_t)s * 1024 * 1024
                        : (ty == 1) ? WKVT + (size_t)s * 512 * 1024
                                    : WOT + (size_t)s * 1024 * 1024;
    int r = t >> 3, c4 = (t & 7) * 4;
    f32x4 v = *(const f32x4*)(src + (size_t)(k0 + r) * N + n0 + c4);
    tile[r][c4 + 0] = v.x; tile[r][c4 + 1] = v.y;
    tile[r][c4 + 2] = v.z; tile[r][c4 + 3] = v.w;
    __syncthreads();
    int nn = t >> 3, kk = (t & 7) * 4;
    bf16x4 o;
    o.x = (short)f2bf(tile[kk + 0][nn]);
    o.y = (short)f2bf(tile[kk + 1][nn]);
    o.z = (short)f2bf(tile[kk + 2][nn]);
    o.w = (short)f2bf(tile[kk + 3][nn]);
    *(bf16x4*)(dst + (size_t)(n0 + nn) * 1024 + k0 + kk) = o;
  } else {
    int b = bid - 6400;
    int s = b >> 11, row = b & 2047;
    const float* src = (s == 0 ? xa : xx) + (size_t)row * DIMM;
    const float* g = (s == 0 ? ga : gx);
    f32x4 v = *(const f32x4*)(src + t * 4);
    float ss = v.x * v.x + v.y * v.y + v.z * v.z + v.w * v.w;
#pragma unroll
    for (int o = 32; o > 0; o >>= 1) ss += __shfl_xor(ss, o, 64);
    if ((t & 63) == 0) red[t >> 6] = ss;
    __syncthreads();
    float tot = red[0] + red[1] + red[2] + red[3];
    float rs = rsqrtf(tot * (1.0f / DIMM) + 1e-6f);
    f32x4 gv = *(const f32x4*)(g + t * 4);
    bf16x4 o;
    o.x = (short)f2bf(v.x * rs * gv.x);
    o.y = (short)f2bf(v.y * rs * gv.y);
    o.z = (short)f2bf(v.z * rs * gv.z);
    o.w = (short)f2bf(v.w * rs * gv.w);
    *(bf16x4*)(XN + ((size_t)s * NSEQ + row) * DIMM + t * 4) = o;
  }
}

// ---- shared 128x128x(K=1024) bf16 NT GEMM mainloop (BK=32, 4 waves) -------
// Staging via global_load_lds (16B/lane): thread t's LDS slot = t*16 bytes,
// which matches [row=t>>2][col=(t&3)*8] of the 128x32 tile.
__device__ __forceinline__ void gemm128_mainloop(
    const unsigned short* __restrict__ Ag, const unsigned short* __restrict__ Bg,
    unsigned short* As, unsigned short* Bs, f32x4 acc[4][4]) {
  int t = threadIdx.x;
  int lane = t & 63, wid = t >> 6;
  int wm = (wid >> 1) * 64, wn = (wid & 1) * 64;
  int l15 = lane & 15, quad = lane >> 4;
  int srow = t >> 2, sko = (t & 3) * 8;
  const unsigned short* ga = Ag + (size_t)srow * 1024 + sko;
  const unsigned short* gb = Bg + (size_t)srow * 1024 + sko;
  unsigned short* la = As + t * 8;
  unsigned short* lb = Bs + t * 8;
#pragma unroll
  for (int mi = 0; mi < 4; ++mi)
#pragma unroll
    for (int j = 0; j < 4; ++j) acc[mi][j] = (f32x4){0.f, 0.f, 0.f, 0.f};
  for (int kt = 0; kt < 32; ++kt) {
    int k0 = kt * 32;
    __syncthreads();                       // prev tile's frag reads done
    glds16(ga + k0, la);
    glds16(ga + 64 * 1024 + k0, la + 2048);
    glds16(gb + k0, lb);
    glds16(gb + 64 * 1024 + k0, lb + 2048);
    __syncthreads();                       // drains vmcnt -> LDS visible
    bf16x8 af[4], bfr[4];
#pragma unroll
    for (int mi = 0; mi < 4; ++mi)
      af[mi] = *(const bf16x8*)(As + (wm + mi * 16 + l15) * 32 + quad * 8);
#pragma unroll
    for (int j = 0; j < 4; ++j)
      bfr[j] = *(const bf16x8*)(Bs + (wn + j * 16 + l15) * 32 + quad * 8);
#pragma unroll
    for (int mi = 0; mi < 4; ++mi)
#pragma unroll
      for (int j = 0; j < 4; ++j)
        acc[mi][j] = __builtin_amdgcn_mfma_f32_16x16x32_bf16(af[mi], bfr[j],
                                                             acc[mi][j], 0, 0, 0);
  }
}

// ------ QKV GEMM: A=[an;xn] (4096x1024), N=1536 (Q 1024 | K 256 | V 256) ---
// Epilogue: RoPE on q/k; q also carries both softmax scales AND log2(e).
// Layouts QB[h][jr][d], KB[h][jr][d]; V written DIRECTLY transposed to
// VT[256(h*64+d)][4096] as packed 8B stores (r-consecutive jr).
__global__ __launch_bounds__(256) void gemm_qkv_kernel(
    const unsigned short* __restrict__ XN, const unsigned short* __restrict__ WQT,
    const unsigned short* __restrict__ WKVT, const float* __restrict__ cosT,
    const float* __restrict__ sinT, unsigned short* __restrict__ QB,
    unsigned short* __restrict__ KB, unsigned short* __restrict__ VT) {
  __shared__ unsigned short As[128 * 32], Bs[128 * 32];
  int n0 = blockIdx.x * 128, m0 = blockIdx.y * 128;
  int s = (m0 >= 2048) ? 1 : 0;
  const unsigned short* Ag = XN + (size_t)m0 * 1024;
  const unsigned short* Bg = (n0 < 1024)
      ? WQT + (size_t)s * 1024 * 1024 + (size_t)n0 * 1024
      : WKVT + (size_t)s * 512 * 1024 + (size_t)(n0 - 1024) * 1024;
  f32x4 acc[4][4];
  gemm128_mainloop(Ag, Bg, As, Bs, acc);
  int t = threadIdx.x, lane = t & 63, wid = t >> 6;
  int wm = (wid >> 1) * 64, wn = (wid & 1) * 64;
  int l15 = lane & 15, quad = lane >> 4;
  int coln = n0 + wn;                     // 64-aligned -> head-uniform per wave
  if (coln < 1280) {
    bool isq = coln < 1024;
    float sc = isq ? (1.4426950408889634f / 64.0f) : 1.0f;  // 1/64 * log2(e)
    unsigned short* dstBase;
    if (isq) dstBase = QB + (size_t)(coln >> 6) * NJ * 64;
    else     dstBase = KB + (size_t)((coln - 1024) >> 6) * NJ * 64;
#pragma unroll
    for (int mi = 0; mi < 4; ++mi)
#pragma unroll
      for (int r = 0; r < 4; ++r) {
        int jr = m0 + wm + mi * 16 + quad * 4 + r;   // joint row (a:0..2047, x:2048..)
        int pos = jr & 2047;
#pragma unroll
        for (int jp = 0; jp < 2; ++jp) {             // d = jp*16+l15 pairs with d+32
          int i = jp * 16 + l15;
          float c = cosT[pos * 32 + i], sn = sinT[pos * 32 + i];
          float x1 = acc[mi][jp][r], x2 = acc[mi][jp + 2][r];
          dstBase[(size_t)jr * 64 + jp * 16 + l15]      = f2bf((x1 * c - x2 * sn) * sc);
          dstBase[(size_t)jr * 64 + 32 + jp * 16 + l15] = f2bf((x2 * c + x1 * sn) * sc);
        }
      }
  } else {
    // V: write straight to VT[d][jr] -- acc[mi][j][0..3] are 4 consecutive jr
    int cvb = coln - 1280;
#pragma unroll
    for (int mi = 0; mi < 4; ++mi)
#pragma unroll
      for (int j = 0; j < 4; ++j) {
        int d = cvb + j * 16 + l15;                  // 0..255 = hk*64 + dh
        int jr0 = m0 + wm + mi * 16 + quad * 4;
        union { bf16x4 v; uint32_t u[2]; } pv;
        pv.u[0] = pack2bf(acc[mi][j][0], acc[mi][j][1]);
        pv.u[1] = pack2bf(acc[mi][j][2], acc[mi][j][3]);
        *(bf16x4*)(VT + (size_t)d * NJ + jr0) = pv.v;
      }
  }
}

// ------------- flash attention: 128 q-rows x 1 head per block --------------
// S^T path (A=K-frag, B=Q-frag) with PERMUTED K-row order: LDS row read for
// block jb, lane m: g(jb,m) = 32*(jb>>1) + 8*(m>>2) + 4*(jb&1) + (m&3).
// Result: lane (q,l15)'s exp'd S^T values for block-pair sb are exactly keys
// 32sb+8q+0..7 -> pack in-place into a 16x16x32 B-frag (natural key order).
// PV: O^T[d][q] += V^T-frag (contiguous bf16x8) x P^T-frag, FULL-RATE K=32.
// lsum via ones-row MFMA. K/V LDS double-buffered (pad 76), 1 barrier/tile.
__global__ __launch_bounds__(256, 4) void attn_kernel(
    const unsigned short* __restrict__ QB, const unsigned short* __restrict__ KB,
    const unsigned short* __restrict__ VT, unsigned short* __restrict__ AT) {
  __shared__ unsigned short Ks[2][64 * LPAD];
  __shared__ unsigned short Vs[2][64 * LPAD];
  int h = blockIdx.y, qt = blockIdx.x;
  int hk = h & 3;                               // jnp.tile -> kv head = h % 4
  int t = threadIdx.x, lane = t & 63, w = t >> 6;
  int l15 = lane & 15, quad = lane >> 4;
  int q0 = qt * 128 + w * 16;                   // m-frag mi rows: q0 + mi*64
  int pl = ((l15 >> 2) << 3) + (l15 & 3);       // permuted-row lane base
  bf16x8 qf[2][2];
#pragma unroll
  for (int mi = 0; mi < 2; ++mi) {
    const unsigned short* qp = QB + ((size_t)h * NJ + q0 + mi * 64 + l15) * 64;
    qf[mi][0] = *(const bf16x8*)(qp + quad * 8);
    qf[mi][1] = *(const bf16x8*)(qp + 32 + quad * 8);
  }
  f32x4 oT[2][4];                               // O^T: row=d(quad*4+r), col=q(l15)
  f32x4 oL[2];                                  // ones-row accum (row0 = lsum)
#pragma unroll
  for (int mi = 0; mi < 2; ++mi) {
    oL[mi] = (f32x4){0.f, 0.f, 0.f, 0.f};
#pragma unroll
    for (int db = 0; db < 4; ++db) oT[mi][db] = (f32x4){0.f, 0.f, 0.f, 0.f};
  }
  // ones A-frag for K=32: A[m][k] = (m==0) ? 1.0 : 0
  bf16x8 vone;
  {
    short one = (l15 == 0) ? (short)0x3F80 : (short)0;
    vone = (bf16x8){one, one, one, one, one, one, one, one};
  }
  const unsigned short* Kg = KB + (size_t)hk * NJ * 64;   // [key][d]
  const unsigned short* Vg = VT + (size_t)hk * 64 * NJ;   // [d][key]
  int ky = t >> 3, dof = (t & 7) * 8;
  const unsigned short* KgA = Kg + (size_t)ky * 64 + dof;        // +tile*4096
  const unsigned short* KgB = Kg + (size_t)(32 + ky) * 64 + dof;
  const unsigned short* VgA = Vg + (size_t)ky * NJ + dof;        // +tile*64
  const unsigned short* VgB = Vg + (size_t)(32 + ky) * NJ + dof;
  // preload tile 0 -> buf0; prefetch tile 1 -> regs
  bf16x8 kr0 = *(const bf16x8*)(KgA);
  bf16x8 kr1 = *(const bf16x8*)(KgB);
  bf16x8 vr0 = *(const bf16x8*)(VgA);
  bf16x8 vr1 = *(const bf16x8*)(VgB);
  *(bf16x8*)(Ks[0] + ky * LPAD + dof) = kr0;
  *(bf16x8*)(Ks[0] + (32 + ky) * LPAD + dof) = kr1;
  *(bf16x8*)(Vs[0] + ky * LPAD + dof) = vr0;
  *(bf16x8*)(Vs[0] + (32 + ky) * LPAD + dof) = vr1;
  kr0 = *(const bf16x8*)(KgA + 4096);
  kr1 = *(const bf16x8*)(KgB + 4096);
  vr0 = *(const bf16x8*)(VgA + 64);
  vr1 = *(const bf16x8*)(VgB + 64);
  __syncthreads();
  for (int kt = 0; kt < 64; ++kt) {
    int cur = kt & 1;
    // write tile kt+1 into other buffer (covered by tile kt-1 compute);
    // issue tile kt+2 loads (drained at end-of-iter barrier).
    unsigned short* Kd = Ks[cur ^ 1];
    unsigned short* Vd = Vs[cur ^ 1];
    *(bf16x8*)(Kd + ky * LPAD + dof) = kr0;
    *(bf16x8*)(Kd + (32 + ky) * LPAD + dof) = kr1;
    *(bf16x8*)(Vd + ky * LPAD + dof) = vr0;
    *(bf16x8*)(Vd + (32 + ky) * LPAD + dof) = vr1;
    int tn = (kt + 2) & 63;                     // wrap: harmless rewrite at end
    kr0 = *(const bf16x8*)(KgA + (size_t)tn * 4096);
    kr1 = *(const bf16x8*)(KgB + (size_t)tn * 4096);
    vr0 = *(const bf16x8*)(VgA + tn * 64);
    vr1 = *(const bf16x8*)(VgB + tn * 64);
    // ---- compute tile kt from buf cur ----
    const unsigned short* Kc = Ks[cur];
    const unsigned short* Vc = Vs[cur];
    // QK, jb-major, PERMUTED rows: C row m of block jb holds key g(jb,m)
    f32x4 sx[2][4];
#pragma unroll
    for (int jb = 0; jb < 4; ++jb) {
      int row = ((jb >> 1) << 5) + ((jb & 1) << 2) + pl;
      const unsigned short* kp = Kc + row * LPAD;
      bf16x8 kf0 = *(const bf16x8*)(kp + quad * 8);
      bf16x8 kf1 = *(const bf16x8*)(kp + 32 + quad * 8);
      f32x4 z0 = (f32x4){0.f, 0.f, 0.f, 0.f};
      z0 = __builtin_amdgcn_mfma_f32_16x16x32_bf16(kf0, qf[0][0], z0, 0, 0, 0);
      z0 = __builtin_amdgcn_mfma_f32_16x16x32_bf16(kf1, qf[0][1], z0, 0, 0, 0);
      sx[0][jb] = z0;
      f32x4 z1 = (f32x4){0.f, 0.f, 0.f, 0.f};
      z1 = __builtin_amdgcn_mfma_f32_16x16x32_bf16(kf0, qf[1][0], z1, 0, 0, 0);
      z1 = __builtin_amdgcn_mfma_f32_16x16x32_bf16(kf1, qf[1][1], z1, 0, 0, 0);
      sx[1][jb] = z1;
    }
    // exp (native) + pack: lane's 8 values of pair sb = keys 32sb+8q+0..7
    // = exactly the 16x16x32 B-frag (k=quad*8+e, n=l15), natural key order.
    bf16x8 pb[2][2];
#pragma unroll
    for (int mi = 0; mi < 2; ++mi)
#pragma unroll
      for (int sb = 0; sb < 2; ++sb) {
        union { bf16x8 v; uint32_t u[4]; } pk;
        pk.u[0] = pack2bf(FAST_EXP2(sx[mi][2 * sb][0]), FAST_EXP2(sx[mi][2 * sb][1]));
        pk.u[1] = pack2bf(FAST_EXP2(sx[mi][2 * sb][2]), FAST_EXP2(sx[mi][2 * sb][3]));
        pk.u[2] = pack2bf(FAST_EXP2(sx[mi][2 * sb + 1][0]), FAST_EXP2(sx[mi][2 * sb + 1][1]));
        pk.u[3] = pack2bf(FAST_EXP2(sx[mi][2 * sb + 1][2]), FAST_EXP2(sx[mi][2 * sb + 1][3]));
        pb[mi][sb] = pk.v;
      }
    // PV at K=32: va contiguous bf16x8 (A: m=d, k=key 32sb+quad*8+e)
#pragma unroll
    for (int db = 0; db < 4; ++db)
#pragma unroll
      for (int sb = 0; sb < 2; ++sb) {
        bf16x8 va = *(const bf16x8*)(Vc + (db * 16 + l15) * LPAD + sb * 32 + quad * 8);
        oT[0][db] = __builtin_amdgcn_mfma_f32_16x16x32_bf16(va, pb[0][sb],
                                                            oT[0][db], 0, 0, 0);
        oT[1][db] = __builtin_amdgcn_mfma_f32_16x16x32_bf16(va, pb[1][sb],
                                                            oT[1][db], 0, 0, 0);
      }
    // lsum rows (row0 of oL accumulates key-sums)
#pragma unroll
    for (int mi = 0; mi < 2; ++mi)
#pragma unroll
      for (int sb = 0; sb < 2; ++sb)
        oL[mi] = __builtin_amdgcn_mfma_f32_16x16x32_bf16(vone, pb[mi][sb],
                                                         oL[mi], 0, 0, 0);
    __syncthreads();                            // reads of buf cur done; drains
  }                                             // prefetch (covered by compute)
  // oL row0 lives on quad==0 -> sum across quads; normalize + write AT
#pragma unroll
  for (int mi = 0; mi < 2; ++mi) {
    float s = oL[mi][0];
    s += __shfl_xor(s, 16, 64);
    s += __shfl_xor(s, 32, 64);
    float inv = 1.0f / s;
    int qrow = q0 + mi * 64 + l15;
#pragma unroll
    for (int db = 0; db < 4; ++db) {
      union { bf16x4 v; uint32_t u[2]; } ov;
      ov.u[0] = pack2bf(oT[mi][db][0] * inv, oT[mi][db][1] * inv);
      ov.u[1] = pack2bf(oT[mi][db][2] * inv, oT[mi][db][3] * inv);
      *(bf16x4*)(AT + (size_t)qrow * DIMM + h * 64 + db * 16 + quad * 4) = ov.v;
    }
  }
}

// ---------------- output GEMM: AT (4096x1024) @ Wout^T + bias -> f32 -------
__global__ __launch_bounds__(256) void gemm_out_kernel(
    const unsigned short* __restrict__ AT, const unsigned short* __restrict__ WOT,
    const float* __restrict__ ba, const float* __restrict__ bx,
    float* __restrict__ out) {
  __shared__ unsigned short As[128 * 32], Bs[128 * 32];
  int n0 = blockIdx.x * 128, m0 = blockIdx.y * 128;
  int s = (m0 >= 2048) ? 1 : 0;                 // 0 = a-stream rows, 1 = x
  const unsigned short* Ag = AT + (size_t)m0 * 1024;
  const unsigned short* Bg = WOT + (size_t)s * 1024 * 1024 + (size_t)n0 * 1024;
  f32x4 acc[4][4];
  gemm128_mainloop(Ag, Bg, As, Bs, acc);
  int t = threadIdx.x, lane = t & 63, wid = t >> 6;
  int wm = (wid >> 1) * 64, wn = (wid & 1) * 64;
  int l15 = lane & 15, quad = lane >> 4;
  const float* bias = s ? bx : ba;
  // d_out = [out_x (2048x1024) | out_a (2048x1024)]
  float* obase = s ? (out + (size_t)(m0 - 2048) * 1024)
                   : (out + (size_t)2048 * 1024 + (size_t)m0 * 1024);
#pragma unroll
  for (int mi = 0; mi < 4; ++mi)
#pragma unroll
    for (int r = 0; r < 4; ++r) {
      int row = wm + mi * 16 + quad * 4 + r;
#pragma unroll
      for (int j = 0; j < 4; ++j) {
        int col = n0 + wn + j * 16 + l15;
        obase[(size_t)row * 1024 + col] = acc[mi][j][r] + bias[col];
      }
    }
}

// ---------------------------------------------------------------------------
extern "C" void kernel_launch(void* const* d_in, const int* in_sizes, int n_in,
                              void* d_out, int out_size, void* d_ws, size_t ws_size,
                              hipStream_t stream) {
  const float* x      = (const float*)d_in[0];
  const float* a      = (const float*)d_in[1];
  const float* g_x    = (const float*)d_in[2];
  const float* g_a    = (const float*)d_in[3];
  const float* Wq_x   = (const float*)d_in[4];
  const float* Wkv_x  = (const float*)d_in[5];
  const float* Wq_a   = (const float*)d_in[6];
  const float* Wkv_a  = (const float*)d_in[7];
  const float* Wout_x = (const float*)d_in[8];
  const float* bout_x = (const float*)d_in[9];
  const float* Wout_a = (const float*)d_in[10];
  const float* bout_a = (const float*)d_in[11];
  float* out = (float*)d_out;

  // workspace (30.5 MB). AT aliases XN (dead after gemm_qkv).
  char* ws = (char*)d_ws;
  const size_t MB = 1024 * 1024;
  unsigned short* XN   = (unsigned short*)(ws);            // 8 MB
  unsigned short* WQT  = (unsigned short*)(ws + 8 * MB);   // 4 MB
  unsigned short* WKVT = (unsigned short*)(ws + 12 * MB);  // 2 MB
  unsigned short* WOT  = (unsigned short*)(ws + 14 * MB);  // 4 MB
  unsigned short* QB   = (unsigned short*)(ws + 18 * MB);  // 8 MB
  unsigned short* KB   = (unsigned short*)(ws + 26 * MB);  // 2 MB
  unsigned short* VT   = (unsigned short*)(ws + 28 * MB);  // 2 MB
  float* cosT          = (float*)(ws + 30 * MB);           // 256 KB
  float* sinT          = (float*)(ws + 30 * MB + 262144);  // 256 KB
  unsigned short* AT   = XN;                               // alias

  prep_kernel<<<dim3(10496), dim3(256), 0, stream>>>(
      a, x, g_a, g_x, Wq_a, Wq_x, Wkv_a, Wkv_x, Wout_a, Wout_x,
      XN, WQT, WKVT, WOT, cosT, sinT);
  gemm_qkv_kernel<<<dim3(12, 32), dim3(256), 0, stream>>>(
      XN, WQT, WKVT, cosT, sinT, QB, KB, VT);
  attn_kernel<<<dim3(32, 16), dim3(256), 0, stream>>>(QB, KB, VT, AT);
  gemm_out_kernel<<<dim3(8, 32), dim3(256), 0, stream>>>(
      AT, WOT, bout_a, bout_x, out);
}

// Round 8
// 232.315 us; speedup vs baseline: 1.7783x; 1.7783x over previous
//
#include <hip/hip_runtime.h>
#include <hip/hip_bf16.h>
#include <stdint.h>
#include <math.h>

// ---------------------------------------------------------------------------
// JointAttention: dual-stream rmsnorm -> QKV proj -> RoPE -> joint attention
// over concat(a, x) (4096 tokens, 16 q-heads, 4 kv-heads tiled h%4) -> out proj.
// All matmuls in bf16 MFMA, fp32 accumulate.
//
// R8 = R7 with the LDS alignment regression fixed:
//  - R7's LPAD=76 made row stride 152 B (8 mod 16) -> every odd-row
//    ds_read/write_b128 was misaligned -> HW slow path (attn 275us, both
//    pipes idle, SQ_LDS_BANK_CONFLICT==0). LPAD back to 72 (144 B = 9*16).
//  - K-row permutation moved to the WRITE side: key k stored at LDS row
//    p(k) = (k&0x23)|((k&0x18)>>1)|((k&0x04)<<2); kf reads use plain rows
//    jb*16+l15 (R6's 2-way-free pattern). Row m of block jb holds key
//    g(jb,m) = 32(jb>>1)+8(m>>2)+4(jb&1)+(m&3), so each lane's exp'd S^T
//    C-frag packs directly into a FULL-RATE 16x16x32 PV B-frag (keys
//    32sb+8q+0..7, natural order); V^T A-frags are contiguous bf16x8.
//  - 20 MFMA/tile-wave (8 QK + 8 PV + 4 lsum), all K=32.
// ---------------------------------------------------------------------------

#define NSEQ 2048
#define NJ   4096
#define DIMM 1024
#define LPAD 72

typedef __attribute__((ext_vector_type(4))) float f32x4;
typedef __attribute__((ext_vector_type(8))) short bf16x8;
typedef __attribute__((ext_vector_type(4))) short bf16x4;

__device__ __forceinline__ unsigned short f2bf(float f) {
  union { float f; uint32_t u; } v; v.f = f;
  return (unsigned short)((v.u + 0x7FFFu + ((v.u >> 16) & 1u)) >> 16);
}

__device__ __forceinline__ uint32_t pack2bf(float a, float b) {
  __hip_bfloat162 h = __float22bfloat162_rn(float2{a, b});
  union { __hip_bfloat162 h; uint32_t u; } c; c.h = h;
  return c.u;
}

#if defined(__has_builtin)
#if __has_builtin(__builtin_amdgcn_exp2f)
#define FAST_EXP2(x) __builtin_amdgcn_exp2f(x)
#endif
#endif
#ifndef FAST_EXP2
#define FAST_EXP2(x) exp2f(x)
#endif

// async global->LDS, 16B per lane; LDS dest = wave-uniform base + lane*16
__device__ __forceinline__ void glds16(const void* g, void* l) {
  __builtin_amdgcn_global_load_lds(
      (const __attribute__((address_space(1))) unsigned int*)g,
      (__attribute__((address_space(3))) unsigned int*)l, 16, 0, 0);
}

// ---------------- fused prep: rope tables + weight cast + rmsnorm ----------
// flat grid, block-uniform branch:
//   [0,256)        rope tables (fp64 trig)
//   [256,6400)     weight cast+transpose f32[1024][N] -> bf16[N][1024]
//   [6400,10496)   rmsnorm + bf16 cast
__global__ __launch_bounds__(256) void prep_kernel(
    const float* __restrict__ xa, const float* __restrict__ xx,
    const float* __restrict__ ga, const float* __restrict__ gx,
    const float* __restrict__ wqa, const float* __restrict__ wqx,
    const float* __restrict__ wkva, const float* __restrict__ wkvx,
    const float* __restrict__ woa, const float* __restrict__ wox,
    unsigned short* __restrict__ XN, unsigned short* __restrict__ WQT,
    unsigned short* __restrict__ WKVT, unsigned short* __restrict__ WOT,
    float* __restrict__ cosT, float* __restrict__ sinT) {
  __shared__ float tile[32][33];
  __shared__ float red[4];
  int bid = blockIdx.x, t = threadIdx.x;
  if (bid < 256) {
    int idx = bid * 256 + t;                    // exactly NSEQ*32
    int pos = idx >> 5, i = idx & 31;
    double inv = pow(10000.0, -(double)i / 32.0);
    double ang = (double)(2 * pos) * inv;       // t = pos * (4096/2048)
    cosT[idx] = (float)cos(ang);
    sinT[idx] = (float)sin(ang);
  } else if (bid < 6400) {
    int b = bid - 256;
    int z = b >> 10, yx = b & 1023;
    int n0 = (yx >> 5) * 32, k0 = (yx & 31) * 32;
    int s = z & 1, ty = z >> 1;
    int N = (ty == 1) ? 512 : 1024;
    if (n0 >= N) return;                        // block-uniform
    const float* src = (z == 0) ? wqa : (z == 1) ? wqx : (z == 2) ? wkva
                     : (z == 3) ? wkvx : (z == 4) ? woa : wox;
    unsigned short* dst = (ty == 0) ? WQT + (size_t)s * 1024 * 1024
                        : (ty == 1) ? WKVT + (size_t)s * 512 * 1024
                                    : WOT + (size_t)s * 1024 * 1024;
    int r = t >> 3, c4 = (t & 7) * 4;
    f32x4 v = *(const f32x4*)(src + (size_t)(k0 + r) * N + n0 + c4);
    tile[r][c4 + 0] = v.x; tile[r][c4 + 1] = v.y;
    tile[r][c4 + 2] = v.z; tile[r][c4 + 3] = v.w;
    __syncthreads();
    int nn = t >> 3, kk = (t & 7) * 4;
    bf16x4 o;
    o.x = (short)f2bf(tile[kk + 0][nn]);
    o.y = (short)f2bf(tile[kk + 1][nn]);
    o.z = (short)f2bf(tile[kk + 2][nn]);
    o.w = (short)f2bf(tile[kk + 3][nn]);
    *(bf16x4*)(dst + (size_t)(n0 + nn) * 1024 + k0 + kk) = o;
  } else {
    int b = bid - 6400;
    int s = b >> 11, row = b & 2047;
    const float* src = (s == 0 ? xa : xx) + (size_t)row * DIMM;
    const float* g = (s == 0 ? ga : gx);
    f32x4 v = *(const f32x4*)(src + t * 4);
    float ss = v.x * v.x + v.y * v.y + v.z * v.z + v.w * v.w;
#pragma unroll
    for (int o = 32; o > 0; o >>= 1) ss += __shfl_xor(ss, o, 64);
    if ((t & 63) == 0) red[t >> 6] = ss;
    __syncthreads();
    float tot = red[0] + red[1] + red[2] + red[3];
    float rs = rsqrtf(tot * (1.0f / DIMM) + 1e-6f);
    f32x4 gv = *(const f32x4*)(g + t * 4);
    bf16x4 o;
    o.x = (short)f2bf(v.x * rs * gv.x);
    o.y = (short)f2bf(v.y * rs * gv.y);
    o.z = (short)f2bf(v.z * rs * gv.z);
    o.w = (short)f2bf(v.w * rs * gv.w);
    *(bf16x4*)(XN + ((size_t)s * NSEQ + row) * DIMM + t * 4) = o;
  }
}

// ---- shared 128x128x(K=1024) bf16 NT GEMM mainloop (BK=32, 4 waves) -------
// Staging via global_load_lds (16B/lane): thread t's LDS slot = t*16 bytes,
// which matches [row=t>>2][col=(t&3)*8] of the 128x32 tile.
__device__ __forceinline__ void gemm128_mainloop(
    const unsigned short* __restrict__ Ag, const unsigned short* __restrict__ Bg,
    unsigned short* As, unsigned short* Bs, f32x4 acc[4][4]) {
  int t = threadIdx.x;
  int lane = t & 63, wid = t >> 6;
  int wm = (wid >> 1) * 64, wn = (wid & 1) * 64;
  int l15 = lane & 15, quad = lane >> 4;
  int srow = t >> 2, sko = (t & 3) * 8;
  const unsigned short* ga = Ag + (size_t)srow * 1024 + sko;
  const unsigned short* gb = Bg + (size_t)srow * 1024 + sko;
  unsigned short* la = As + t * 8;
  unsigned short* lb = Bs + t * 8;
#pragma unroll
  for (int mi = 0; mi < 4; ++mi)
#pragma unroll
    for (int j = 0; j < 4; ++j) acc[mi][j] = (f32x4){0.f, 0.f, 0.f, 0.f};
  for (int kt = 0; kt < 32; ++kt) {
    int k0 = kt * 32;
    __syncthreads();                       // prev tile's frag reads done
    glds16(ga + k0, la);
    glds16(ga + 64 * 1024 + k0, la + 2048);
    glds16(gb + k0, lb);
    glds16(gb + 64 * 1024 + k0, lb + 2048);
    __syncthreads();                       // drains vmcnt -> LDS visible
    bf16x8 af[4], bfr[4];
#pragma unroll
    for (int mi = 0; mi < 4; ++mi)
      af[mi] = *(const bf16x8*)(As + (wm + mi * 16 + l15) * 32 + quad * 8);
#pragma unroll
    for (int j = 0; j < 4; ++j)
      bfr[j] = *(const bf16x8*)(Bs + (wn + j * 16 + l15) * 32 + quad * 8);
#pragma unroll
    for (int mi = 0; mi < 4; ++mi)
#pragma unroll
      for (int j = 0; j < 4; ++j)
        acc[mi][j] = __builtin_amdgcn_mfma_f32_16x16x32_bf16(af[mi], bfr[j],
                                                             acc[mi][j], 0, 0, 0);
  }
}

// ------ QKV GEMM: A=[an;xn] (4096x1024), N=1536 (Q 1024 | K 256 | V 256) ---
// Epilogue: RoPE on q/k; q also carries both softmax scales AND log2(e).
// Layouts QB[h][jr][d], KB[h][jr][d]; V written DIRECTLY transposed to
// VT[256(h*64+d)][4096] as packed 8B stores (r-consecutive jr).
__global__ __launch_bounds__(256) void gemm_qkv_kernel(
    const unsigned short* __restrict__ XN, const unsigned short* __restrict__ WQT,
    const unsigned short* __restrict__ WKVT, const float* __restrict__ cosT,
    const float* __restrict__ sinT, unsigned short* __restrict__ QB,
    unsigned short* __restrict__ KB, unsigned short* __restrict__ VT) {
  __shared__ unsigned short As[128 * 32], Bs[128 * 32];
  int n0 = blockIdx.x * 128, m0 = blockIdx.y * 128;
  int s = (m0 >= 2048) ? 1 : 0;
  const unsigned short* Ag = XN + (size_t)m0 * 1024;
  const unsigned short* Bg = (n0 < 1024)
      ? WQT + (size_t)s * 1024 * 1024 + (size_t)n0 * 1024
      : WKVT + (size_t)s * 512 * 1024 + (size_t)(n0 - 1024) * 1024;
  f32x4 acc[4][4];
  gemm128_mainloop(Ag, Bg, As, Bs, acc);
  int t = threadIdx.x, lane = t & 63, wid = t >> 6;
  int wm = (wid >> 1) * 64, wn = (wid & 1) * 64;
  int l15 = lane & 15, quad = lane >> 4;
  int coln = n0 + wn;                     // 64-aligned -> head-uniform per wave
  if (coln < 1280) {
    bool isq = coln < 1024;
    float sc = isq ? (1.4426950408889634f / 64.0f) : 1.0f;  // 1/64 * log2(e)
    unsigned short* dstBase;
    if (isq) dstBase = QB + (size_t)(coln >> 6) * NJ * 64;
    else     dstBase = KB + (size_t)((coln - 1024) >> 6) * NJ * 64;
#pragma unroll
    for (int mi = 0; mi < 4; ++mi)
#pragma unroll
      for (int r = 0; r < 4; ++r) {
        int jr = m0 + wm + mi * 16 + quad * 4 + r;   // joint row (a:0..2047, x:2048..)
        int pos = jr & 2047;
#pragma unroll
        for (int jp = 0; jp < 2; ++jp) {             // d = jp*16+l15 pairs with d+32
          int i = jp * 16 + l15;
          float c = cosT[pos * 32 + i], sn = sinT[pos * 32 + i];
          float x1 = acc[mi][jp][r], x2 = acc[mi][jp + 2][r];
          dstBase[(size_t)jr * 64 + jp * 16 + l15]      = f2bf((x1 * c - x2 * sn) * sc);
          dstBase[(size_t)jr * 64 + 32 + jp * 16 + l15] = f2bf((x2 * c + x1 * sn) * sc);
        }
      }
  } else {
    // V: write straight to VT[d][jr] -- acc[mi][j][0..3] are 4 consecutive jr
    int cvb = coln - 1280;
#pragma unroll
    for (int mi = 0; mi < 4; ++mi)
#pragma unroll
      for (int j = 0; j < 4; ++j) {
        int d = cvb + j * 16 + l15;                  // 0..255 = hk*64 + dh
        int jr0 = m0 + wm + mi * 16 + quad * 4;
        union { bf16x4 v; uint32_t u[2]; } pv;
        pv.u[0] = pack2bf(acc[mi][j][0], acc[mi][j][1]);
        pv.u[1] = pack2bf(acc[mi][j][2], acc[mi][j][3]);
        *(bf16x4*)(VT + (size_t)d * NJ + jr0) = pv.v;
      }
  }
}

// ------------- flash attention: 128 q-rows x 1 head per block --------------
// K staged PERMUTED (key k -> LDS row p(k)); kf reads use plain rows
// jb*16+l15 so row m of block jb holds key g(jb,m). Lane (q,l15)'s exp'd
// S^T values for block-pair sb are keys 32sb+8q+0..7 -> direct K=32 PV
// B-frag. V natural order; V^T A-frags contiguous bf16x8. lsum via ones-row
// MFMA. K/V LDS double-buffered (pad 72 = 16B-aligned rows), 1 barrier/tile.
__global__ __launch_bounds__(256, 4) void attn_kernel(
    const unsigned short* __restrict__ QB, const unsigned short* __restrict__ KB,
    const unsigned short* __restrict__ VT, unsigned short* __restrict__ AT) {
  __shared__ unsigned short Ks[2][64 * LPAD];
  __shared__ unsigned short Vs[2][64 * LPAD];
  int h = blockIdx.y, qt = blockIdx.x;
  int hk = h & 3;                               // jnp.tile -> kv head = h % 4
  int t = threadIdx.x, lane = t & 63, w = t >> 6;
  int l15 = lane & 15, quad = lane >> 4;
  int q0 = qt * 128 + w * 16;                   // m-frag mi rows: q0 + mi*64
  bf16x8 qf[2][2];
#pragma unroll
  for (int mi = 0; mi < 2; ++mi) {
    const unsigned short* qp = QB + ((size_t)h * NJ + q0 + mi * 64 + l15) * 64;
    qf[mi][0] = *(const bf16x8*)(qp + quad * 8);
    qf[mi][1] = *(const bf16x8*)(qp + 32 + quad * 8);
  }
  f32x4 oT[2][4];                               // O^T: row=d(quad*4+r), col=q(l15)
  f32x4 oL[2];                                  // ones-row accum (row0 = lsum)
#pragma unroll
  for (int mi = 0; mi < 2; ++mi) {
    oL[mi] = (f32x4){0.f, 0.f, 0.f, 0.f};
#pragma unroll
    for (int db = 0; db < 4; ++db) oT[mi][db] = (f32x4){0.f, 0.f, 0.f, 0.f};
  }
  // ones A-frag for K=32: A[m][k] = (m==0) ? 1.0 : 0
  bf16x8 vone;
  {
    short one = (l15 == 0) ? (short)0x3F80 : (short)0;
    vone = (bf16x8){one, one, one, one, one, one, one, one};
  }
  const unsigned short* Kg = KB + (size_t)hk * NJ * 64;   // [key][d]
  const unsigned short* Vg = VT + (size_t)hk * 64 * NJ;   // [d][key]
  int ky = t >> 3, dof = (t & 7) * 8;
  // write-side permutation: key k -> LDS row p(k); p(k+32) = p(k)+32
  int pky = (ky & 0x23) | ((ky & 0x18) >> 1) | ((ky & 0x04) << 2);
  const unsigned short* KgA = Kg + (size_t)ky * 64 + dof;        // +tile*4096
  const unsigned short* KgB = Kg + (size_t)(32 + ky) * 64 + dof;
  const unsigned short* VgA = Vg + (size_t)ky * NJ + dof;        // +tile*64
  const unsigned short* VgB = Vg + (size_t)(32 + ky) * NJ + dof;
  // preload tile 0 -> buf0; prefetch tile 1 -> regs
  bf16x8 kr0 = *(const bf16x8*)(KgA);
  bf16x8 kr1 = *(const bf16x8*)(KgB);
  bf16x8 vr0 = *(const bf16x8*)(VgA);
  bf16x8 vr1 = *(const bf16x8*)(VgB);
  *(bf16x8*)(Ks[0] + pky * LPAD + dof) = kr0;
  *(bf16x8*)(Ks[0] + (32 + pky) * LPAD + dof) = kr1;
  *(bf16x8*)(Vs[0] + ky * LPAD + dof) = vr0;
  *(bf16x8*)(Vs[0] + (32 + ky) * LPAD + dof) = vr1;
  kr0 = *(const bf16x8*)(KgA + 4096);
  kr1 = *(const bf16x8*)(KgB + 4096);
  vr0 = *(const bf16x8*)(VgA + 64);
  vr1 = *(const bf16x8*)(VgB + 64);
  __syncthreads();
  for (int kt = 0; kt < 64; ++kt) {
    int cur = kt & 1;
    // write tile kt+1 into other buffer (covered by tile kt-1 compute);
    // issue tile kt+2 loads (drained at end-of-iter barrier).
    unsigned short* Kd = Ks[cur ^ 1];
    unsigned short* Vd = Vs[cur ^ 1];
    *(bf16x8*)(Kd + pky * LPAD + dof) = kr0;
    *(bf16x8*)(Kd + (32 + pky) * LPAD + dof) = kr1;
    *(bf16x8*)(Vd + ky * LPAD + dof) = vr0;
    *(bf16x8*)(Vd + (32 + ky) * LPAD + dof) = vr1;
    int tn = (kt + 2) & 63;                     // wrap: harmless rewrite at end
    kr0 = *(const bf16x8*)(KgA + (size_t)tn * 4096);
    kr1 = *(const bf16x8*)(KgB + (size_t)tn * 4096);
    vr0 = *(const bf16x8*)(VgA + tn * 64);
    vr1 = *(const bf16x8*)(VgB + tn * 64);
    // ---- compute tile kt from buf cur ----
    const unsigned short* Kc = Ks[cur];
    const unsigned short* Vc = Vs[cur];
    // QK, jb-major, plain rows (content permuted at write time)
    f32x4 sx[2][4];
#pragma unroll
    for (int jb = 0; jb < 4; ++jb) {
      const unsigned short* kp = Kc + (jb * 16 + l15) * LPAD;
      bf16x8 kf0 = *(const bf16x8*)(kp + quad * 8);
      bf16x8 kf1 = *(const bf16x8*)(kp + 32 + quad * 8);
      f32x4 z0 = (f32x4){0.f, 0.f, 0.f, 0.f};
      z0 = __builtin_amdgcn_mfma_f32_16x16x32_bf16(kf0, qf[0][0], z0, 0, 0, 0);
      z0 = __builtin_amdgcn_mfma_f32_16x16x32_bf16(kf1, qf[0][1], z0, 0, 0, 0);
      sx[0][jb] = z0;
      f32x4 z1 = (f32x4){0.f, 0.f, 0.f, 0.f};
      z1 = __builtin_amdgcn_mfma_f32_16x16x32_bf16(kf0, qf[1][0], z1, 0, 0, 0);
      z1 = __builtin_amdgcn_mfma_f32_16x16x32_bf16(kf1, qf[1][1], z1, 0, 0, 0);
      sx[1][jb] = z1;
    }
    // exp (native) + pack: lane's 8 values of pair sb = keys 32sb+8q+0..7
    // = exactly the 16x16x32 B-frag (k=quad*8+e, n=l15), natural key order.
    bf16x8 pb[2][2];
#pragma unroll
    for (int mi = 0; mi < 2; ++mi)
#pragma unroll
      for (int sb = 0; sb < 2; ++sb) {
        union { bf16x8 v; uint32_t u[4]; } pk;
        pk.u[0] = pack2bf(FAST_EXP2(sx[mi][2 * sb][0]), FAST_EXP2(sx[mi][2 * sb][1]));
        pk.u[1] = pack2bf(FAST_EXP2(sx[mi][2 * sb][2]), FAST_EXP2(sx[mi][2 * sb][3]));
        pk.u[2] = pack2bf(FAST_EXP2(sx[mi][2 * sb + 1][0]), FAST_EXP2(sx[mi][2 * sb + 1][1]));
        pk.u[3] = pack2bf(FAST_EXP2(sx[mi][2 * sb + 1][2]), FAST_EXP2(sx[mi][2 * sb + 1][3]));
        pb[mi][sb] = pk.v;
      }
    // PV at K=32: va contiguous bf16x8 (A: m=d, k=key 32sb+quad*8+e)
#pragma unroll
    for (int db = 0; db < 4; ++db)
#pragma unroll
      for (int sb = 0; sb < 2; ++sb) {
        bf16x8 va = *(const bf16x8*)(Vc + (db * 16 + l15) * LPAD + sb * 32 + quad * 8);
        oT[0][db] = __builtin_amdgcn_mfma_f32_16x16x32_bf16(va, pb[0][sb],
                                                            oT[0][db], 0, 0, 0);
        oT[1][db] = __builtin_amdgcn_mfma_f32_16x16x32_bf16(va, pb[1][sb],
                                                            oT[1][db], 0, 0, 0);
      }
    // lsum rows (row0 of oL accumulates key-sums)
#pragma unroll
    for (int mi = 0; mi < 2; ++mi)
#pragma unroll
      for (int sb = 0; sb < 2; ++sb)
        oL[mi] = __builtin_amdgcn_mfma_f32_16x16x32_bf16(vone, pb[mi][sb],
                                                         oL[mi], 0, 0, 0);
    __syncthreads();                            // reads of buf cur done; drains
  }                                             // prefetch (covered by compute)
  // oL row0 lives on quad==0 -> sum across quads; normalize + write AT
#pragma unroll
  for (int mi = 0; mi < 2; ++mi) {
    float s = oL[mi][0];
    s += __shfl_xor(s, 16, 64);
    s += __shfl_xor(s, 32, 64);
    float inv = 1.0f / s;
    int qrow = q0 + mi * 64 + l15;
#pragma unroll
    for (int db = 0; db < 4; ++db) {
      union { bf16x4 v; uint32_t u[2]; } ov;
      ov.u[0] = pack2bf(oT[mi][db][0] * inv, oT[mi][db][1] * inv);
      ov.u[1] = pack2bf(oT[mi][db][2] * inv, oT[mi][db][3] * inv);
      *(bf16x4*)(AT + (size_t)qrow * DIMM + h * 64 + db * 16 + quad * 4) = ov.v;
    }
  }
}

// ---------------- output GEMM: AT (4096x1024) @ Wout^T + bias -> f32 -------
__global__ __launch_bounds__(256) void gemm_out_kernel(
    const unsigned short* __restrict__ AT, const unsigned short* __restrict__ WOT,
    const float* __restrict__ ba, const float* __restrict__ bx,
    float* __restrict__ out) {
  __shared__ unsigned short As[128 * 32], Bs[128 * 32];
  int n0 = blockIdx.x * 128, m0 = blockIdx.y * 128;
  int s = (m0 >= 2048) ? 1 : 0;                 // 0 = a-stream rows, 1 = x
  const unsigned short* Ag = AT + (size_t)m0 * 1024;
  const unsigned short* Bg = WOT + (size_t)s * 1024 * 1024 + (size_t)n0 * 1024;
  f32x4 acc[4][4];
  gemm128_mainloop(Ag, Bg, As, Bs, acc);
  int t = threadIdx.x, lane = t & 63, wid = t >> 6;
  int wm = (wid >> 1) * 64, wn = (wid & 1) * 64;
  int l15 = lane & 15, quad = lane >> 4;
  const float* bias = s ? bx : ba;
  // d_out = [out_x (2048x1024) | out_a (2048x1024)]
  float* obase = s ? (out + (size_t)(m0 - 2048) * 1024)
                   : (out + (size_t)2048 * 1024 + (size_t)m0 * 1024);
#pragma unroll
  for (int mi = 0; mi < 4; ++mi)
#pragma unroll
    for (int r = 0; r < 4; ++r) {
      int row = wm + mi * 16 + quad * 4 + r;
#pragma unroll
      for (int j = 0; j < 4; ++j) {
        int col = n0 + wn + j * 16 + l15;
        obase[(size_t)row * 1024 + col] = acc[mi][j][r] + bias[col];
      }
    }
}

// ---------------------------------------------------------------------------
extern "C" void kernel_launch(void* const* d_in, const int* in_sizes, int n_in,
                              void* d_out, int out_size, void* d_ws, size_t ws_size,
                              hipStream_t stream) {
  const float* x      = (const float*)d_in[0];
  const float* a      = (const float*)d_in[1];
  const float* g_x    = (const float*)d_in[2];
  const float* g_a    = (const float*)d_in[3];
  const float* Wq_x   = (const float*)d_in[4];
  const float* Wkv_x  = (const float*)d_in[5];
  const float* Wq_a   = (const float*)d_in[6];
  const float* Wkv_a  = (const float*)d_in[7];
  const float* Wout_x = (const float*)d_in[8];
  const float* bout_x = (const float*)d_in[9];
  const float* Wout_a = (const float*)d_in[10];
  const float* bout_a = (const float*)d_in[11];
  float* out = (float*)d_out;

  // workspace (30.5 MB). AT aliases XN (dead after gemm_qkv).
  char* ws = (char*)d_ws;
  const size_t MB = 1024 * 1024;
  unsigned short* XN   = (unsigned short*)(ws);            // 8 MB
  unsigned short* WQT  = (unsigned short*)(ws + 8 * MB);   // 4 MB
  unsigned short* WKVT = (unsigned short*)(ws + 12 * MB);  // 2 MB
  unsigned short* WOT  = (unsigned short*)(ws + 14 * MB);  // 4 MB
  unsigned short* QB   = (unsigned short*)(ws + 18 * MB);  // 8 MB
  unsigned short* KB   = (unsigned short*)(ws + 26 * MB);  // 2 MB
  unsigned short* VT   = (unsigned short*)(ws + 28 * MB);  // 2 MB
  float* cosT          = (float*)(ws + 30 * MB);           // 256 KB
  float* sinT          = (float*)(ws + 30 * MB + 262144);  // 256 KB
  unsigned short* AT   = XN;                               // alias

  prep_kernel<<<dim3(10496), dim3(256), 0, stream>>>(
      a, x, g_a, g_x, Wq_a, Wq_x, Wkv_a, Wkv_x, Wout_a, Wout_x,
      XN, WQT, WKVT, WOT, cosT, sinT);
  gemm_qkv_kernel<<<dim3(12, 32), dim3(256), 0, stream>>>(
      XN, WQT, WKVT, cosT, sinT, QB, KB, VT);
  attn_kernel<<<dim3(32, 16), dim3(256), 0, stream>>>(QB, KB, VT, AT);
  gemm_out_kernel<<<dim3(8, 32), dim3(256), 0, stream>>>(
      AT, WOT, bout_a, bout_x, out);
}